// Round 1
// baseline (755.502 us; speedup 1.0000x reference)
//
#include <hip/hip_runtime.h>
#include <math.h>

// Problem constants (from reference)
constexpr int cB = 8, cT = 2048, cDU = 512, cDM = 512, cDA = 256, cDF = 12, cL = 4;
constexpr float cEPS = 1e-6f;
constexpr float cSCALE = 16.0f;   // sqrt(DA=256)
constexpr float cGAMMA = 1.0f;

// ---------------- workspace layout (float offsets) ----------------
constexpr size_t KOFF  = 0;                                  // k: B*T*DA
constexpr size_t VOFF  = KOFF + (size_t)cB * cT * cDA;       // v: B*T*DU
constexpr size_t SBOFF = VOFF + (size_t)cB * cT * cDU;       // sbias: B*T
constexpr size_t UNOFF = SBOFF + (size_t)cB * cT;            // unorm2: B*T
constexpr size_t LGOFF = UNOFF + (size_t)cB * cT;            // logits: B*T
constexpr size_t YOFF  = LGOFF + (size_t)cB * cT;            // y: B*T
constexpr size_t PROFF = YOFF + (size_t)cB * cT;             // prev: B*T
constexpr size_t OVOFF = PROFF + (size_t)cB * cT;            // overlap / ydist: B*T
constexpr size_t QOFF  = OVOFF + (size_t)cB * cT;            // q: B*DA
constexpr size_t MOFF  = QOFF + (size_t)cB * cDA;            // memory: B*DM
constexpr size_t ZOFF  = MOFF + (size_t)cB * cDM;            // z: B*DU  (zero per stage)
constexpr size_t COFF  = ZOFF + (size_t)cB * cDU;            // centroid: B*DU (zero per stage)
constexpr size_t GIOFF = COFF + (size_t)cB * cDU;            // gi: B*1536
constexpr size_t GHOFF = GIOFF + (size_t)cB * 3 * cDM;       // gh: B*1536
constexpr size_t SCOFF = GHOFF + (size_t)cB * 3 * cDM;       // scalars: B*8
// scal indices: 0 ysum_clamped, 1 coverage, 2 entropy, 3 wsq, 4 spread, 5 compact, 6 csq, 7 cen2

__device__ __forceinline__ float wave_sum(float v) {
#pragma unroll
  for (int o = 32; o; o >>= 1) v += __shfl_down(v, o);
  return v;
}

// block reductions for 1024-thread blocks
__device__ __forceinline__ float block_reduce_sum(float v, float* red) {
  int tid = threadIdx.x;
  red[tid] = v; __syncthreads();
  for (int s = 512; s; s >>= 1) { if (tid < s) red[tid] += red[tid + s]; __syncthreads(); }
  float r = red[0]; __syncthreads();
  return r;
}
__device__ __forceinline__ float block_reduce_max(float v, float* red) {
  int tid = threadIdx.x;
  red[tid] = v; __syncthreads();
  for (int s = 512; s; s >>= 1) { if (tid < s) red[tid] = fmaxf(red[tid], red[tid + s]); __syncthreads(); }
  float r = red[0]; __syncthreads();
  return r;
}

// ---------------- precompute: sbias + unorm2 (one wave per (b,t)) ----------------
__global__ void k_pre(const float* __restrict__ sf, const float* __restrict__ u,
                      const float* __restrict__ w1, const float* __restrict__ b1,
                      const float* __restrict__ w2, const float* __restrict__ b2,
                      float* __restrict__ sbias, float* __restrict__ unorm2) {
  int wid = (blockIdx.x * blockDim.x + threadIdx.x) >> 6;   // b*T+t
  int lane = threadIdx.x & 63;
  float d0 = sf[(size_t)wid * cDF + 8];
  float d1 = sf[(size_t)wid * cDF + 9];
  float d2 = sf[(size_t)wid * cDF + 10];
  float acc = 0.f;
#pragma unroll
  for (int i = 0; i < 4; ++i) {
    int a = lane * 4 + i;
    float h = d0 * w1[a * 3 + 0] + d1 * w1[a * 3 + 1] + d2 * w1[a * 3 + 2] + b1[a];
    float g = 0.5f * h * (1.0f + erff(h * 0.70710678118654752f));  // exact gelu
    acc += g * w2[a];
  }
  float un = 0.f;
  const float4* ur = (const float4*)(u + (size_t)wid * cDU);
#pragma unroll
  for (int m = 0; m < 2; ++m) {
    float4 x = ur[lane + m * 64];
    un += x.x * x.x + x.y * x.y + x.z * x.z + x.w * x.w;
  }
  acc = wave_sum(acc);
  un = wave_sum(un);
  if (lane == 0) { sbias[wid] = acc + b2[0]; unorm2[wid] = un; }
}

// ---------------- fp32 tiled GEMM: C[M,N] = A[M,K] @ Bw[N,K]^T ----------------
__global__ __launch_bounds__(256) void gemm_abt(const float* __restrict__ A,
                                                const float* __restrict__ Bw,
                                                float* __restrict__ C,
                                                int M, int N, int K) {
  __shared__ float As[32][68];
  __shared__ float Bs[32][68];
  const int tid = threadIdx.x;
  const int m0 = blockIdx.y * 64;
  const int n0 = blockIdx.x * 64;
  const int ty = tid >> 4, tx = tid & 15;
  const int lr = tid >> 3;
  const int lc = (tid & 7) << 2;
  float acc[4][4] = {};
  for (int k0 = 0; k0 < K; k0 += 32) {
    float4 a0 = *(const float4*)&A[(size_t)(m0 + lr) * K + k0 + lc];
    float4 a1 = *(const float4*)&A[(size_t)(m0 + lr + 32) * K + k0 + lc];
    float4 b0 = *(const float4*)&Bw[(size_t)(n0 + lr) * K + k0 + lc];
    float4 b1 = *(const float4*)&Bw[(size_t)(n0 + lr + 32) * K + k0 + lc];
    __syncthreads();
    As[lc + 0][lr] = a0.x; As[lc + 1][lr] = a0.y; As[lc + 2][lr] = a0.z; As[lc + 3][lr] = a0.w;
    As[lc + 0][lr + 32] = a1.x; As[lc + 1][lr + 32] = a1.y; As[lc + 2][lr + 32] = a1.z; As[lc + 3][lr + 32] = a1.w;
    Bs[lc + 0][lr] = b0.x; Bs[lc + 1][lr] = b0.y; Bs[lc + 2][lr] = b0.z; Bs[lc + 3][lr] = b0.w;
    Bs[lc + 0][lr + 32] = b1.x; Bs[lc + 1][lr + 32] = b1.y; Bs[lc + 2][lr + 32] = b1.z; Bs[lc + 3][lr + 32] = b1.w;
    __syncthreads();
#pragma unroll
    for (int kk = 0; kk < 32; ++kk) {
      float4 av = *(const float4*)&As[kk][ty << 2];
      float4 bv = *(const float4*)&Bs[kk][tx << 2];
      float a[4] = {av.x, av.y, av.z, av.w};
      float b[4] = {bv.x, bv.y, bv.z, bv.w};
#pragma unroll
      for (int i = 0; i < 4; ++i)
#pragma unroll
        for (int j = 0; j < 4; ++j)
          acc[i][j] += a[i] * b[j];
    }
  }
#pragma unroll
  for (int i = 0; i < 4; ++i) {
    float4 o = make_float4(acc[i][0], acc[i][1], acc[i][2], acc[i][3]);
    *(float4*)&C[(size_t)(m0 + (ty << 2) + i) * N + n0 + (tx << 2)] = o;
  }
}

// ---------------- q = memory @ Wq^T (wave per (b,a)) ----------------
__global__ void k_q(const float* __restrict__ mem, const float* __restrict__ Wq,
                    float* __restrict__ q) {
  int wid = (blockIdx.x * blockDim.x + threadIdx.x) >> 6;  // b*DA + a
  int lane = threadIdx.x & 63;
  int b = wid >> 8, a = wid & 255;
  const float4* mr = (const float4*)(mem + (size_t)b * cDM);
  const float4* wr = (const float4*)(Wq + (size_t)a * cDM);
  float acc = 0.f;
#pragma unroll
  for (int m = 0; m < 2; ++m) {
    float4 x = mr[lane + m * 64], w = wr[lane + m * 64];
    acc += x.x * w.x + x.y * w.y + x.z * w.z + x.w * w.w;
  }
  acc = wave_sum(acc);
  if (lane == 0) q[wid] = acc;
}

// ---------------- logits = (k.q/SCALE + sbias - gamma*sim@prev)/temp ----------------
__global__ void k_logits(const float* __restrict__ kbuf, const float* __restrict__ q,
                         const float* __restrict__ sbias, const float* __restrict__ sim,
                         const float* __restrict__ prev, const float* __restrict__ log_temp,
                         float gamma, float* __restrict__ logits) {
  int wid = (blockIdx.x * blockDim.x + threadIdx.x) >> 6;  // b*T+t
  int lane = threadIdx.x & 63;
  int b = wid >> 11;
  const float4* kr = (const float4*)(kbuf + (size_t)wid * cDA);
  const float4* qr = (const float4*)(q + (size_t)b * cDA);
  float4 kx = kr[lane];
  float4 qx = qr[lane];
  float acc = (kx.x * qx.x + kx.y * qx.y + kx.z * qx.z + kx.w * qx.w) * (1.0f / cSCALE);
  if (gamma != 0.0f) {
    const float4* sr = (const float4*)(sim + (size_t)wid * cT);
    const float4* pr = (const float4*)(prev + (size_t)b * cT);
    float sd = 0.f;
#pragma unroll
    for (int m = 0; m < 8; ++m) {
      float4 s = sr[lane + m * 64];
      float4 p = pr[lane + m * 64];
      sd += s.x * p.x + s.y * p.y + s.z * p.z + s.w * p.w;
    }
    acc -= gamma * sd;
  }
  acc = wave_sum(acc);
  if (lane == 0) {
    float temp = fminf(fmaxf(expf(log_temp[0]), 0.1f), 10.0f);
    logits[wid] = (acc + sbias[wid]) / temp;
  }
}

// ---------------- softmax over T per b ----------------
__global__ __launch_bounds__(1024) void k_softmax(const float* __restrict__ logits,
                                                  float* __restrict__ y) {
  __shared__ float red[1024];
  int b = blockIdx.x, tid = threadIdx.x;
  int i0 = b * cT + tid, i1 = i0 + 1024;
  float l0 = logits[i0], l1 = logits[i1];
  float m = block_reduce_max(fmaxf(l0, l1), red);
  float e0 = expf(l0 - m), e1 = expf(l1 - m);
  float S = block_reduce_sum(e0 + e1, red);
  y[i0] = e0 / S; y[i1] = e1 / S;
}

// ---------------- overlap = sim @ y ----------------
__global__ void k_overlap(const float* __restrict__ sim, const float* __restrict__ y,
                          float* __restrict__ overlap) {
  int wid = (blockIdx.x * blockDim.x + threadIdx.x) >> 6;
  int lane = threadIdx.x & 63;
  int b = wid >> 11;
  const float4* sr = (const float4*)(sim + (size_t)wid * cT);
  const float4* yr = (const float4*)(y + (size_t)b * cT);
  float acc = 0.f;
#pragma unroll
  for (int m = 0; m < 8; ++m) {
    float4 s = sr[lane + m * 64];
    float4 yy = yr[lane + m * 64];
    acc += s.x * yy.x + s.y * yy.y + s.z * yy.z + s.w * yy.w;
  }
  acc = wave_sum(acc);
  if (lane == 0) overlap[wid] = acc;
}

// ---------------- penalty + softmax#2 + prev update + scalar stats ----------------
__global__ __launch_bounds__(1024) void k_soft2(const float* __restrict__ overlap,
                                                const float* __restrict__ logits,
                                                float* __restrict__ y, float* __restrict__ prev,
                                                const float* __restrict__ unorm2,
                                                float* __restrict__ scal, int first_stage) {
  __shared__ float red[1024];
  int b = blockIdx.x, tid = threadIdx.x;
  int i0 = b * cT + tid, i1 = i0 + 1024;
  float o0 = overlap[i0], o1 = overlap[i1];
  float mo = fmaxf(block_reduce_max(fmaxf(o0, o1), red), cEPS);
  float l0 = logits[i0] - o0 / mo;
  float l1 = logits[i1] - o1 / mo;
  float ml = block_reduce_max(fmaxf(l0, l1), red);
  float e0 = expf(l0 - ml), e1 = expf(l1 - ml);
  float S = block_reduce_sum(e0 + e1, red);
  float y0 = e0 / S, y1 = e1 / S;
  y[i0] = y0; y[i1] = y1;
  if (first_stage) { prev[i0] = y0; prev[i1] = y1; }
  else             { prev[i0] += y0; prev[i1] += y1; }
  float ysr = block_reduce_sum(y0 + y1, red);
  float ysc = fmaxf(ysr, cEPS);
  float wsq = block_reduce_sum(y0 * unorm2[i0] + y1 * unorm2[i1], red);
  float yn0 = y0 / ysc, yn1 = y1 / ysc;
  float ent = block_reduce_sum(-yn0 * logf(fmaxf(yn0, cEPS)) - yn1 * logf(fmaxf(yn1, cEPS)), red);
  if (tid == 0) {
    scal[b * 8 + 0] = ysc;
    scal[b * 8 + 1] = ysr / (float)cT;   // coverage
    scal[b * 8 + 2] = ent;
    scal[b * 8 + 3] = wsq;
  }
}

// ---------------- z = y@v, centroid = y@u (t-chunked, atomic) ----------------
__global__ __launch_bounds__(256) void k_zc(const float* __restrict__ y,
                                            const float* __restrict__ v,
                                            const float* __restrict__ u,
                                            float* __restrict__ zbuf, float* __restrict__ cbuf) {
  int b = blockIdx.y;
  int tc = blockIdx.x;             // 32 chunks of 64 t
  int d = threadIdx.x;             // handles d and d+256
  float z0 = 0.f, z1 = 0.f, c0 = 0.f, c1 = 0.f;
  for (int i = 0; i < 64; ++i) {
    int t = tc * 64 + i;
    float yv = y[b * cT + t];
    const float* vr = v + (size_t)(b * cT + t) * cDU;
    const float* ur = u + (size_t)(b * cT + t) * cDU;
    z0 += yv * vr[d];       z1 += yv * vr[d + 256];
    c0 += yv * ur[d];       c1 += yv * ur[d + 256];
  }
  atomicAdd(&zbuf[b * cDU + d], z0);       atomicAdd(&zbuf[b * cDU + d + 256], z1);
  atomicAdd(&cbuf[b * cDU + d], c0);       atomicAdd(&cbuf[b * cDU + d + 256], c1);
}

// ---------------- normalize centroid, csq, cen2 ----------------
__global__ __launch_bounds__(256) void k_cen(float* __restrict__ cbuf, float* __restrict__ scal) {
  __shared__ float red[256];
  int b = blockIdx.x, tid = threadIdx.x;
  float ysc = scal[b * 8 + 0];
  float c0 = cbuf[b * cDU + tid], c1 = cbuf[b * cDU + tid + 256];
  float n0 = c0 / ysc, n1 = c1 / ysc;
  cbuf[b * cDU + tid] = n0; cbuf[b * cDU + tid + 256] = n1;
  red[tid] = c0 * c0 + c1 * c1; __syncthreads();
  for (int s = 128; s; s >>= 1) { if (tid < s) red[tid] += red[tid + s]; __syncthreads(); }
  float csq = red[0]; __syncthreads();
  red[tid] = n0 * n0 + n1 * n1; __syncthreads();
  for (int s = 128; s; s >>= 1) { if (tid < s) red[tid] += red[tid + s]; __syncthreads(); }
  if (tid == 0) { scal[b * 8 + 6] = csq; scal[b * 8 + 7] = red[0]; }
}

// ---------------- ydist[b,t] = y * || u - cen ||  (wave per (b,t)) ----------------
__global__ void k_ydist(const float* __restrict__ u, const float* __restrict__ cen,
                        const float* __restrict__ unorm2, const float* __restrict__ y,
                        const float* __restrict__ scal, float* __restrict__ ydist) {
  int wid = (blockIdx.x * blockDim.x + threadIdx.x) >> 6;
  int lane = threadIdx.x & 63;
  int b = wid >> 11;
  const float4* ur = (const float4*)(u + (size_t)wid * cDU);
  const float4* cr = (const float4*)(cen + (size_t)b * cDU);
  float dot = 0.f;
#pragma unroll
  for (int m = 0; m < 2; ++m) {
    float4 a = ur[lane + m * 64];
    float4 c = cr[lane + m * 64];
    dot += a.x * c.x + a.y * c.y + a.z * c.z + a.w * c.w;
  }
  dot = wave_sum(dot);
  if (lane == 0) {
    float d2 = unorm2[wid] - 2.f * dot + scal[b * 8 + 7];
    ydist[wid] = y[wid] * sqrtf(fmaxf(d2, 0.f));
  }
}

// ---------------- spread + compact scalars ----------------
__global__ __launch_bounds__(1024) void k_spread(const float* __restrict__ ydist,
                                                 float* __restrict__ scal) {
  __shared__ float red[1024];
  int b = blockIdx.x, tid = threadIdx.x;
  float v = ydist[b * cT + tid] + ydist[b * cT + tid + 1024];
  float s = block_reduce_sum(v, red);
  if (tid == 0) {
    float ysc = scal[b * 8 + 0], wsq = scal[b * 8 + 3], csq = scal[b * 8 + 6];
    scal[b * 8 + 4] = s / ysc;
    scal[b * 8 + 5] = 2.f * (ysc * wsq - csq) / fmaxf(ysc * ysc, cEPS);
  }
}

// ---------------- gi = x@W_ih^T + b_ih ; gh = mem@W_hh^T + b_hh (wave per (b,j)) ------
__global__ __launch_bounds__(256) void k_gru_mm(const float* __restrict__ zbuf,
                                                const float* __restrict__ scal,
                                                const float* __restrict__ mem,
                                                const float* __restrict__ W_ih,
                                                const float* __restrict__ b_ih,
                                                const float* __restrict__ W_hh,
                                                const float* __restrict__ b_hh,
                                                float* __restrict__ gi, float* __restrict__ gh) {
  int b = blockIdx.y;
  int j = (blockIdx.x * blockDim.x + threadIdx.x) >> 6;  // 0..1535
  int lane = threadIdx.x & 63;
  float accI = 0.f, accH = 0.f;
  const float4* xz = (const float4*)(zbuf + (size_t)b * cDU);
  const float4* wI = (const float4*)(W_ih + (size_t)j * (cDU + 4));
#pragma unroll
  for (int m = 0; m < 3; ++m) {
    int i4 = lane + m * 64;
    if (i4 < 128) {
      float4 x = xz[i4]; float4 w = wI[i4];
      accI += x.x * w.x + x.y * w.y + x.z * w.z + x.w * w.w;
    } else if (i4 == 128) {  // c = [coverage, entropy, spread, compact]
      float4 w = wI[128];
      accI += scal[b * 8 + 1] * w.x + scal[b * 8 + 2] * w.y +
              scal[b * 8 + 4] * w.z + scal[b * 8 + 5] * w.w;
    }
  }
  const float4* xm = (const float4*)(mem + (size_t)b * cDM);
  const float4* wH = (const float4*)(W_hh + (size_t)j * cDM);
#pragma unroll
  for (int m = 0; m < 2; ++m) {
    int i4 = lane + m * 64;
    float4 x = xm[i4]; float4 w = wH[i4];
    accH += x.x * w.x + x.y * w.y + x.z * w.z + x.w * w.w;
  }
  accI = wave_sum(accI);
  accH = wave_sum(accH);
  if (lane == 0) {
    gi[b * 1536 + j] = accI + b_ih[j];
    gh[b * 1536 + j] = accH + b_hh[j];
  }
}

// ---------------- GRU gate combine + memory update + output write ----------------
__global__ void k_gru_up(const float* __restrict__ gi, const float* __restrict__ gh,
                         const float* __restrict__ zbuf, float* __restrict__ mem,
                         float* __restrict__ out, int stage) {
  int idx = blockIdx.x * blockDim.x + threadIdx.x;  // b*512 + i
  int b = idx >> 9, i = idx & 511;
  float gir = gi[b * 1536 + i], giz = gi[b * 1536 + 512 + i], gin = gi[b * 1536 + 1024 + i];
  float ghr = gh[b * 1536 + i], ghz = gh[b * 1536 + 512 + i], ghn = gh[b * 1536 + 1024 + i];
  float rg = 1.f / (1.f + expf(-(gir + ghr)));
  float zg = 1.f / (1.f + expf(-(giz + ghz)));
  float ng = tanhf(gin + rg * ghn);
  mem[idx] = (1.f - zg) * ng + zg * mem[idx];
  out[(size_t)(b * cL + stage) * cDU + i] = zbuf[b * cDU + i];
}

extern "C" void kernel_launch(void* const* d_in, const int* in_sizes, int n_in,
                              void* d_out, int out_size, void* d_ws, size_t ws_size,
                              hipStream_t stream) {
  const float* u    = (const float*)d_in[0];
  const float* sf   = (const float*)d_in[1];
  const float* sim  = (const float*)d_in[2];
  const float* mem0 = (const float*)d_in[3];
  const float* Wq   = (const float*)d_in[4];
  const float* Wk   = (const float*)d_in[5];
  const float* Wv   = (const float*)d_in[6];
  const float* sbw1 = (const float*)d_in[7];
  const float* sbb1 = (const float*)d_in[8];
  const float* sbw2 = (const float*)d_in[9];
  const float* sbb2 = (const float*)d_in[10];
  const float* logt = (const float*)d_in[11];
  const float* W_ih = (const float*)d_in[12];
  const float* b_ih = (const float*)d_in[13];
  const float* W_hh = (const float*)d_in[14];
  const float* b_hh = (const float*)d_in[15];
  float* out = (float*)d_out;
  float* ws  = (float*)d_ws;

  const int M = cB * cT;  // 16384

  // precompute sbias + unorm2
  k_pre<<<(cB * cT) / 4, 256, 0, stream>>>(sf, u, sbw1, sbb1, sbw2, sbb2,
                                           ws + SBOFF, ws + UNOFF);
  // k = u @ Wk^T ; v = u @ Wv^T
  gemm_abt<<<dim3(cDA / 64, M / 64), 256, 0, stream>>>(u, Wk, ws + KOFF, M, cDA, cDU);
  gemm_abt<<<dim3(cDU / 64, M / 64), 256, 0, stream>>>(u, Wv, ws + VOFF, M, cDU, cDU);
  // memory = memory0
  hipMemcpyAsync(ws + MOFF, mem0, (size_t)cB * cDM * sizeof(float),
                 hipMemcpyDeviceToDevice, stream);

  for (int stage = 0; stage < cL; ++stage) {
    k_q<<<(cB * cDA) / 4, 256, 0, stream>>>(ws + MOFF, Wq, ws + QOFF);
    k_logits<<<(cB * cT) / 4, 256, 0, stream>>>(ws + KOFF, ws + QOFF, ws + SBOFF, sim,
                                                ws + PROFF, logt,
                                                stage == 0 ? 0.0f : cGAMMA, ws + LGOFF);
    k_softmax<<<cB, 1024, 0, stream>>>(ws + LGOFF, ws + YOFF);
    k_overlap<<<(cB * cT) / 4, 256, 0, stream>>>(sim, ws + YOFF, ws + OVOFF);
    k_soft2<<<cB, 1024, 0, stream>>>(ws + OVOFF, ws + LGOFF, ws + YOFF, ws + PROFF,
                                     ws + UNOFF, ws + SCOFF, stage == 0 ? 1 : 0);
    hipMemsetAsync(ws + ZOFF, 0, (size_t)2 * cB * cDU * sizeof(float), stream);
    k_zc<<<dim3(32, cB), 256, 0, stream>>>(ws + YOFF, ws + VOFF, u, ws + ZOFF, ws + COFF);
    k_cen<<<cB, 256, 0, stream>>>(ws + COFF, ws + SCOFF);
    k_ydist<<<(cB * cT) / 4, 256, 0, stream>>>(u, ws + COFF, ws + UNOFF, ws + YOFF,
                                               ws + SCOFF, ws + OVOFF);
    k_spread<<<cB, 1024, 0, stream>>>(ws + OVOFF, ws + SCOFF);
    k_gru_mm<<<dim3((3 * cDM) / 4, cB), 256, 0, stream>>>(ws + ZOFF, ws + SCOFF, ws + MOFF,
                                                          W_ih, b_ih, W_hh, b_hh,
                                                          ws + GIOFF, ws + GHOFF);
    k_gru_up<<<(cB * cDM) / 256, 256, 0, stream>>>(ws + GIOFF, ws + GHOFF, ws + ZOFF,
                                                   ws + MOFF, out, stage);
  }
}